// Round 22
// baseline (39.242 us; speedup 1.0000x reference)
//
#include <hip/hip_runtime.h>
#include <hip/hip_bf16.h>

typedef short bf16x8 __attribute__((ext_vector_type(8)));
typedef float f32x4  __attribute__((ext_vector_type(4)));
typedef float f32x2  __attribute__((ext_vector_type(2)));

constexpr int HW = 4096;   // 64*64 pixels
constexpr int CT = 31;     // time channels
constexpr int CP = 128;    // poi channels
constexpr int CO = 64;     // output channels

__device__ __forceinline__ short f2bf(float x) {
    __hip_bfloat16 h = __float2bfloat16(x);
    return *reinterpret_cast<short*>(&h);
}
// Issue an 8-byte load NOW; result valid only after the matching vmcnt wait.
__device__ __forceinline__ f32x2 async_load2(const float* p) {
    f32x2 v;
    asm volatile("global_load_dwordx2 %0, %1, off" : "=v"(v) : "v"(p));
    return v;
}
#define VM_WAIT(n) asm volatile("s_waitcnt vmcnt(" #n ")" ::: "memory")
#define SBAR() __builtin_amdgcn_sched_barrier(0)

// Full-line-read variant of mfma7: lane (g,m) loads float2 at px0+2m, so each
// 16-lane g-group reads 128 B contiguous (one full line) per channel — read
// transactions halve vs the 64-B pattern that r9-r21 show to be rate-limited.
// tile0 = even px (.x), tile1 = odd px (.y): feeds both A-fragments with NO
// redistribution. Epilogue shuffle-fixup restores the contiguous store layout
// (64-B store segments, r9-verified). One asm load burst (40x8B) per wave.
// grid = 2048 blocks; block = 2 px-halves x 2 o-halves = 4 waves.
__global__ __launch_bounds__(256)
void poi_mfma8(const float* __restrict__ poi,
               const float* __restrict__ tin,
               const float* __restrict__ wm,
               const float* __restrict__ bm,
               const float* __restrict__ wf,
               const float* __restrict__ bf,
               const float* __restrict__ wc,
               const float* __restrict__ bc,
               float* __restrict__ out)
{
    const int lane = threadIdx.x & 63;
    const int m    = lane & 15;       // o within subtile / px-pair slot
    const int g    = lane >> 4;       // 4-lane group: k-subrange / D row-group
    const int wid  = threadIdx.x >> 6;
    const int oh   = (wid & 1) * 2;   // o-subtiles {oh, oh+1}
    const int b    = blockIdx.x >> 6;                        // 64 blocks/image
    const int px0  = ((blockIdx.x & 63) << 6) + (wid >> 1) * 32;  // 32-px strip

    // ---------- one-time weight fragments (layout verified r8+) ----------
    bf16x8 wcf[2][4];
    #pragma unroll
    for (int s = 0; s < 2; ++s)
      #pragma unroll
      for (int kf = 0; kf < 4; ++kf)
        #pragma unroll
        for (int j = 0; j < 8; ++j)
          wcf[s][kf][j] = f2bf(wc[((oh + s) * 16 + m) * CP + kf * 32 + g * 8 + j]);

    bf16x8 wmf[2];
    #pragma unroll
    for (int t2 = 0; t2 < 2; ++t2)
      #pragma unroll
      for (int j = 0; j < 8; ++j) {
        const int c = g * 8 + j;
        wmf[t2][j] = (c < CT) ? f2bf(wm[(t2 * 16 + m) * CT + c]) : (short)0;
      }
    float wff[8]; f32x4 bmf[2]; float bcf[2];
    #pragma unroll
    for (int t2 = 0; t2 < 2; ++t2)
      #pragma unroll
      for (int r = 0; r < 4; ++r) {
        wff[t2 * 4 + r] = wf[t2 * 16 + g * 4 + r];
        bmf[t2][r]      = bm[t2 * 16 + g * 4 + r];
      }
    #pragma unroll
    for (int s = 0; s < 2; ++s) bcf[s] = bc[(oh + s) * 16 + m];
    const float bfv = bf[0];

    const float* tb = tin + (size_t)b * CT * HW + px0 + 2 * m;
    const float* pb = poi + (size_t)b * CP * HW + px0 + 2 * m;

    SBAR(); VM_WAIT(0); SBAR();       // drain prologue loads: counted waits sound

    // ---- issue ALL 40 float2 loads (program order, 40-deep, full lines) ----
    f32x2 tfr[8];
    #pragma unroll
    for (int j = 0; j < 8; ++j) {
        const int c  = g * 8 + j;
        const int cc = (c < CT) ? c : (CT - 1);      // clamp pad lane
        tfr[j] = async_load2(tb + (size_t)cc * HW);
    }
    f32x2 pfr[32];
    #pragma unroll
    for (int kf = 0; kf < 4; ++kf)
      #pragma unroll
      for (int j = 0; j < 8; ++j)
        pfr[kf * 8 + j] = async_load2(pb + (size_t)(kf * 32 + g * 8 + j) * HW);
    SBAR();
    VM_WAIT(32);                      // 8 tf loads (oldest) have landed
    SBAR();

    // ---- stage 1 x2 (pf in flight): tval = relu(wf.relu(wm@t+bm)+bf) ----
    bf16x8 tf0, tf1;
    #pragma unroll
    for (int j = 0; j < 8; ++j) {
        const int c = g * 8 + j;
        tf0[j] = (c < CT) ? f2bf(tfr[j][0]) : (short)0;   // even px
        tf1[j] = (c < CT) ? f2bf(tfr[j][1]) : (short)0;   // odd px
    }
    f32x4 z0x = __builtin_amdgcn_mfma_f32_16x16x32_bf16(wmf[0], tf0, bmf[0], 0, 0, 0);
    f32x4 z1x = __builtin_amdgcn_mfma_f32_16x16x32_bf16(wmf[1], tf0, bmf[1], 0, 0, 0);
    f32x4 z0y = __builtin_amdgcn_mfma_f32_16x16x32_bf16(wmf[0], tf1, bmf[0], 0, 0, 0);
    f32x4 z1y = __builtin_amdgcn_mfma_f32_16x16x32_bf16(wmf[1], tf1, bmf[1], 0, 0, 0);
    float sx = 0.f, sy = 0.f;
    #pragma unroll
    for (int r = 0; r < 4; ++r) {
        sx = fmaf(fmaxf(z0x[r], 0.f), wff[r],     sx);
        sx = fmaf(fmaxf(z1x[r], 0.f), wff[4 + r], sx);
        sy = fmaf(fmaxf(z0y[r], 0.f), wff[r],     sy);
        sy = fmaf(fmaxf(z1y[r], 0.f), wff[4 + r], sy);
    }
    sx += __shfl_xor(sx, 16, 64);  sx += __shfl_xor(sx, 32, 64);
    sy += __shfl_xor(sy, 16, 64);  sy += __shfl_xor(sy, 32, 64);
    const float tval0 = fmaxf(sx + bfv, 0.f);     // t(px0 + 2m)
    const float tval1 = fmaxf(sy + bfv, 0.f);     // t(px0 + 2m + 1)
    f32x4 tv0, tv1;                               // transpose to D-row layout
    #pragma unroll
    for (int r = 0; r < 4; ++r) {
        tv0[r] = __shfl(tval0, g * 4 + r, 64);
        tv1[r] = __shfl(tval1, g * 4 + r, 64);
    }

    SBAR();
    VM_WAIT(0);                       // all 32 pf landed
    SBAR();

    // ---- stage 2: A = poi (M=px-slot), B = wc (N=o), K=128 ----
    bf16x8 pf0[4], pf1[4];
    #pragma unroll
    for (int kf = 0; kf < 4; ++kf)
      #pragma unroll
      for (int j = 0; j < 8; ++j) {
        pf0[kf][j] = f2bf(pfr[kf * 8 + j][0]);
        pf1[kf][j] = f2bf(pfr[kf * 8 + j][1]);
      }
    f32x4 a0[2], a1[2];               // [s] for tile0 (even), tile1 (odd)
    #pragma unroll
    for (int s = 0; s < 2; ++s) { a0[s] = f32x4{0.f,0.f,0.f,0.f}; a1[s] = f32x4{0.f,0.f,0.f,0.f}; }
    #pragma unroll
    for (int kf = 0; kf < 4; ++kf) {
        #pragma unroll
        for (int s = 0; s < 2; ++s) {
            a0[s] = __builtin_amdgcn_mfma_f32_16x16x32_bf16(pf0[kf], wcf[s][kf], a0[s], 0, 0, 0);
            a1[s] = __builtin_amdgcn_mfma_f32_16x16x32_bf16(pf1[kf], wcf[s][kf], a1[s], 0, 0, 0);
        }
    }

    // ---- epilogue: lane holds px_local {8g+2r, 8g+2r+1}; shuffle-fixup to
    //      contiguous 16 B/lane, 64-B 4-lane segments (r9-verified shape) ----
    const int srcA = ((g >> 1) << 4) + m;     // lane holding px_local [8*(g/2), +8)
    const int srcB = srcA + 32;               // lane holding px_local [16+8*(g/2), +8)
    #pragma unroll
    for (int s = 0; s < 2; ++s) {
        float v[8];
        #pragma unroll
        for (int r = 0; r < 4; ++r) {
            v[2 * r]     = fmaf(tv0[r], a0[s][r], bcf[s]);   // px_local 8g+2r
            v[2 * r + 1] = fmaf(tv1[r], a1[s][r], bcf[s]);   // px_local 8g+2r+1
        }
        f32x4 lo, hi;
        #pragma unroll
        for (int q = 0; q < 4; ++q) {
            const float aA = __shfl(v[q], srcA, 64);
            const float bA = __shfl(v[q + 4], srcA, 64);
            lo[q] = (g & 1) ? bA : aA;                       // px_local 4g+q
            const float aB = __shfl(v[q], srcB, 64);
            const float bB = __shfl(v[q + 4], srcB, 64);
            hi[q] = (g & 1) ? bB : aB;                       // px_local 16+4g+q
        }
        float* orow = out + (size_t)b * CO * HW
                          + (size_t)((oh + s) * 16 + m) * HW + px0;
        __builtin_nontemporal_store(lo, reinterpret_cast<f32x4*>(orow + 4 * g));
        __builtin_nontemporal_store(hi, reinterpret_cast<f32x4*>(orow + 16 + 4 * g));
    }
}

extern "C" void kernel_launch(void* const* d_in, const int* in_sizes, int n_in,
                              void* d_out, int out_size, void* d_ws, size_t ws_size,
                              hipStream_t stream) {
    const float* poi = (const float*)d_in[0];
    const float* tin = (const float*)d_in[1];
    const float* wm  = (const float*)d_in[2];
    const float* bm  = (const float*)d_in[3];
    const float* wf  = (const float*)d_in[4];
    const float* bf  = (const float*)d_in[5];
    const float* wc  = (const float*)d_in[6];
    const float* bc  = (const float*)d_in[7];
    float* out = (float*)d_out;

    // 32 images x 64 blocks (64 px each); block = 2 px-halves x 2 o-halves
    hipLaunchKernelGGL(poi_mfma8, dim3(2048), dim3(256), 0, stream,
                       poi, tin, wm, bm, wf, bf, wc, bc, out);
}